// Round 1
// baseline (21224.448 us; speedup 1.0000x reference)
//
#include <hip/hip_runtime.h>
#include <math.h>

#define T_ 128
#define B_ 256
#define D_ 128
#define L_ 32
#define C_ 64
#define H_ 256
#define S_ 16
#define R_ 4096   // S*B
#define NT_ 127
#define DT 0.02f
#define SQDT 0.14142135623730951f

__device__ __forceinline__ float sp_(float x){
  return fmaxf(x, 0.f) + __logf(1.f + __expf(-fabsf(x)));
}
__device__ __forceinline__ float sig_(float x){
  return 1.f / (1.f + __expf(-x));
}
__device__ __forceinline__ float tanh_(float x){
  return 1.f - 2.f / (1.f + __expf(2.f * x));
}

// block of 256 threads -> one double atomicAdd
__device__ __forceinline__ void blk_reduce_add(float v, double* acc){
  for (int o = 32; o > 0; o >>= 1) v += __shfl_down(v, o, 64);
  __shared__ float wpart[4];
  int lane = threadIdx.x & 63, w = threadIdx.x >> 6;
  if (lane == 0) wpart[w] = v;
  __syncthreads();
  if (threadIdx.x == 0) atomicAdd(acc, (double)(wpart[0] + wpart[1] + wpart[2] + wpart[3]));
}

__global__ void k_init(double* accs){ if (threadIdx.x < 3) accs[threadIdx.x] = 0.0; }

// xT[t][d][b] = xs_pre[b][t][d]
__global__ void k_tx(const float* __restrict__ xs_pre, float* __restrict__ xT){
  int i = blockIdx.x * 256 + threadIdx.x;
  int b = i & 255; int d = (i >> 8) & 127; int t = i >> 15;
  xT[i] = xs_pre[(b * T_ + t) * D_ + d];
}

// g-weights transposed to [h][l]
__global__ void k_tsmall(const float* __restrict__ gW1, const float* __restrict__ gb1,
                         const float* __restrict__ gW2,
                         float* __restrict__ gW1T, float* __restrict__ gb1T,
                         float* __restrict__ gW2T){
  int i = blockIdx.x * 256 + threadIdx.x;
  int sec = i >> 13, idx = i & 8191;
  int h = idx >> 5, l = idx & 31;
  if (sec == 0) gW1T[idx] = gW1[l * H_ + h];
  else if (sec == 1) gb1T[idx] = gb1[l * H_ + h];
  else gW2T[idx] = gW2[l * H_ + h];
}

// GRU step k (scan over reversed time): hsT[k][jj][b]
__global__ void k_gru(const float* __restrict__ xT, const float* __restrict__ Wih,
                      const float* __restrict__ Whh, const float* __restrict__ bih,
                      const float* __restrict__ bhh, float* __restrict__ hsT, int k){
  int jj = blockIdx.x; int b = threadIdx.x;
  int t = 127 - k;
  const float* xrow = xT + t * D_ * B_ + b;
  const float* wr = Wih + jj * D_;
  const float* wz = Wih + (jj + H_) * D_;
  const float* wn = Wih + (jj + 2 * H_) * D_;
  float gi_r = bih[jj], gi_z = bih[jj + H_], gi_n = bih[jj + 2 * H_];
  #pragma unroll 4
  for (int d = 0; d < D_; ++d){
    float xv = xrow[d * B_];
    gi_r = fmaf(xv, wr[d], gi_r);
    gi_z = fmaf(xv, wz[d], gi_z);
    gi_n = fmaf(xv, wn[d], gi_n);
  }
  float gh_r = bhh[jj], gh_z = bhh[jj + H_], gh_n = bhh[jj + 2 * H_];
  float hprev = 0.f;
  if (k > 0){
    const float* hrow = hsT + (k - 1) * H_ * B_ + b;
    const float* vr = Whh + jj * H_;
    const float* vz = Whh + (jj + H_) * H_;
    const float* vn = Whh + (jj + 2 * H_) * H_;
    #pragma unroll 4
    for (int q = 0; q < H_; ++q){
      float hv = hrow[q * B_];
      gh_r = fmaf(hv, vr[q], gh_r);
      gh_z = fmaf(hv, vz[q], gh_z);
      gh_n = fmaf(hv, vn[q], gh_n);
    }
    hprev = hrow[jj * B_];
  }
  float r = sig_(gi_r + gh_r);
  float u = sig_(gi_z + gh_z);
  float n = tanh_(gi_n + r * gh_n);
  float hn = (1.f - u) * n + u * hprev;
  hsT[k * H_ * B_ + jj * B_ + b] = hn;
}

// ctxT[t][c][b] = hs[127-t] @ encW^T + encb
__global__ void k_ctx(const float* __restrict__ hsT, const float* __restrict__ encW,
                      const float* __restrict__ encb, float* __restrict__ ctxT){
  int b = threadIdx.x;
  int c = blockIdx.x & 63;
  int t = blockIdx.x >> 6;
  const float* hrow = hsT + (127 - t) * H_ * B_ + b;
  const float* w = encW + c * H_;
  float acc = encb[c];
  #pragma unroll 4
  for (int q = 0; q < H_; ++q) acc = fmaf(hrow[q * B_], w[q], acc);
  ctxT[(t * C_ + c) * B_ + b] = acc;
}

// q(z0) head + KL(q||p) reduction
__global__ void k_qz0(const float* __restrict__ ctxT, const float* __restrict__ qW,
                      const float* __restrict__ qb, const float* __restrict__ pm,
                      const float* __restrict__ pls, float* __restrict__ qmT,
                      float* __restrict__ qlsT, double* __restrict__ kl_acc){
  int b = threadIdx.x; int l = blockIdx.x;
  const float* crow = ctxT + b;  // ctxT[0][c][b]
  const float* wm = qW + l * C_;
  const float* ws2 = qW + (L_ + l) * C_;
  float am = qb[l], as = qb[L_ + l];
  for (int c = 0; c < C_; ++c){
    float cv = crow[c * B_];
    am = fmaf(cv, wm[c], am);
    as = fmaf(cv, ws2[c], as);
  }
  qmT[l * B_ + b] = am; qlsT[l * B_ + b] = as;
  float plsl = pls[l], pml = pm[l];
  float dm = am - pml;
  float kl = plsl - as + (__expf(2.f * as) + dm * dm) / (2.f * __expf(2.f * plsl)) - 0.5f;
  blk_reduce_add(kl, kl_acc);
}

// z0 = qm + exp(qls)*eps0 ; write z0T and zs_t[:, :, 0, :]
__global__ void k_z0(const float* __restrict__ eps0, const float* __restrict__ qmT,
                     const float* __restrict__ qlsT, float* __restrict__ z0T,
                     float* __restrict__ zs){
  int r = blockIdx.x * 256 + threadIdx.x;
  int b = r & 255;
  for (int l = 0; l < L_; ++l){
    float z = fmaf(__expf(qlsT[l * B_ + b]), eps0[r * L_ + l], qmT[l * B_ + b]);
    z0T[l * R_ + r] = z;
    zs[r * T_ * L_ + l] = z;
  }
}

#define JC1 16
// layer 1 of f (with ctx) and h; output softplus'd -> ab1T[j][r] (f: j<256, h: j>=256)
__global__ void k_l1(const float* __restrict__ zT, const float* __restrict__ ctxT,
                     const float* __restrict__ fW1, const float* __restrict__ fb1,
                     const float* __restrict__ hW1, const float* __restrict__ hb1,
                     float* __restrict__ ab1T, int tctx){
  int rb = blockIdx.x & 15; int jg = blockIdx.x >> 4;
  int r = rb * 256 + threadIdx.x;
  int j0 = jg * JC1;
  float acc[JC1];
  if (j0 < H_){
    const float* wbase = fW1 + j0 * 96;
    #pragma unroll
    for (int q = 0; q < JC1; ++q) acc[q] = fb1[j0 + q];
    for (int kk = 0; kk < L_; ++kk){
      float zv = zT[kk * R_ + r];
      #pragma unroll
      for (int q = 0; q < JC1; ++q) acc[q] = fmaf(zv, wbase[q * 96 + kk], acc[q]);
    }
    const float* crow = ctxT + tctx * C_ * B_ + (r & 255);
    for (int c = 0; c < C_; ++c){
      float cv = crow[c * B_];
      #pragma unroll
      for (int q = 0; q < JC1; ++q) acc[q] = fmaf(cv, wbase[q * 96 + 32 + c], acc[q]);
    }
  } else {
    const float* wbase = hW1 + (j0 - H_) * L_;
    #pragma unroll
    for (int q = 0; q < JC1; ++q) acc[q] = hb1[j0 - H_ + q];
    for (int kk = 0; kk < L_; ++kk){
      float zv = zT[kk * R_ + r];
      #pragma unroll
      for (int q = 0; q < JC1; ++q) acc[q] = fmaf(zv, wbase[q * L_ + kk], acc[q]);
    }
  }
  #pragma unroll
  for (int q = 0; q < JC1; ++q) ab1T[(j0 + q) * R_ + r] = sp_(acc[q]);
}

// layer 2 of f and h (256x256 each); softplus'd -> ab2T
__global__ void k_l2(const float* __restrict__ ab1T, const float* __restrict__ fW2,
                     const float* __restrict__ fb2, const float* __restrict__ hW2,
                     const float* __restrict__ hb2, float* __restrict__ ab2T){
  int rb = blockIdx.x & 15; int jg = blockIdx.x >> 4;
  int r = rb * 256 + threadIdx.x;
  int j0 = jg * JC1;
  const float* in; const float* w; const float* bb;
  if (j0 < H_){ in = ab1T;            w = fW2 + j0 * H_;        bb = fb2 + j0; }
  else        { in = ab1T + H_ * R_;  w = hW2 + (j0 - H_) * H_; bb = hb2 + (j0 - H_); }
  float acc[JC1];
  #pragma unroll
  for (int q = 0; q < JC1; ++q) acc[q] = bb[q];
  for (int kk = 0; kk < H_; ++kk){
    float v = in[kk * R_ + r];
    #pragma unroll
    for (int q = 0; q < JC1; ++q) acc[q] = fmaf(v, w[q * H_ + kk], acc[q]);
  }
  #pragma unroll
  for (int q = 0; q < JC1; ++q) ab2T[(j0 + q) * R_ + r] = sp_(acc[q]);
}

#define JC3 8
// layer 3: fv (j<32), hv (j>=32) -> fhT[j][r], no activation
__global__ void k_l3(const float* __restrict__ ab2T, const float* __restrict__ fW3,
                     const float* __restrict__ fb3, const float* __restrict__ hW3,
                     const float* __restrict__ hb3, float* __restrict__ fhT){
  int rb = blockIdx.x & 15; int jg = blockIdx.x >> 4;  // 0..7
  int r = rb * 256 + threadIdx.x;
  int j0 = jg * JC3;
  const float* in; const float* w; const float* bb;
  if (j0 < L_){ in = ab2T;           w = fW3 + j0 * H_;        bb = fb3 + j0; }
  else        { in = ab2T + H_ * R_; w = hW3 + (j0 - L_) * H_; bb = hb3 + (j0 - L_); }
  float acc[JC3];
  #pragma unroll
  for (int q = 0; q < JC3; ++q) acc[q] = bb[q];
  for (int kk = 0; kk < H_; ++kk){
    float v = in[kk * R_ + r];
    #pragma unroll
    for (int q = 0; q < JC3; ++q) acc[q] = fmaf(v, w[q * H_ + kk], acc[q]);
  }
  #pragma unroll
  for (int q = 0; q < JC3; ++q) fhT[(j0 + q) * R_ + r] = acc[q];
}

// diagonal g-net + euler update + logqp accumulation; writes znT and zs_t[:, :, k+1, :]
__global__ void k_gu(const float* __restrict__ zT, const float* __restrict__ fhT,
                     const float* __restrict__ gW1T, const float* __restrict__ gb1T,
                     const float* __restrict__ gW2T, const float* __restrict__ gb2,
                     const float* __restrict__ dW, float* __restrict__ znT,
                     float* __restrict__ zs, double* __restrict__ u2_acc, int k){
  int l = threadIdx.x & 31; int rg = threadIdx.x >> 5;
  int r = blockIdx.x * 8 + rg;
  float zl = zT[l * R_ + r];
  float gacc = 0.f;
  #pragma unroll 4
  for (int h = 0; h < H_; ++h){
    float x = fmaf(zl, gW1T[h * L_ + l], gb1T[h * L_ + l]);
    gacc = fmaf(sp_(x), gW2T[h * L_ + l], gacc);
  }
  float gv = sig_(gacc + gb2[l]) + 0.01f;
  float fv = fhT[l * R_ + r];
  float hv = fhT[(L_ + l) * R_ + r];
  float u = (fv - hv) / gv;
  blk_reduce_add(u * u, u2_acc);
  float dwv = dW[k * (S_ * B_ * L_) + r * L_ + l];
  float zn = zl + fv * DT + gv * (SQDT * dwv);
  znT[l * R_ + r] = zn;
  zs[(r * T_ + (k + 1)) * L_ + l] = zn;
}

// Poisson log-likelihood, summed into ell_acc
__global__ void k_pois(const float* __restrict__ zs, const float* __restrict__ Cw,
                       const float* __restrict__ db, const float* __restrict__ xs_pre,
                       double* __restrict__ ell_acc){
  int d = threadIdx.x & 127;
  int row = blockIdx.x * 2 + (threadIdx.x >> 7);   // row = (s*B + b)*T + t
  int t = row & 127; int b = (row >> 7) & 255;
  const float* zrow = zs + row * L_;
  float lr = db[d] - 3.912023005428146f;           // + log(0.02)
  #pragma unroll 8
  for (int l = 0; l < L_; ++l) lr = fmaf(zrow[l], Cw[l * D_ + d], lr);
  float xv = xs_pre[(b * T_ + t) * D_ + d];
  int xi = (int)(xv + 0.5f);
  float lg = (xi <= 1) ? 0.f : (xi == 2 ? 0.6931471805599453f :
             (xi == 3 ? 1.791759469228055f : 3.1780538303479458f));
  float ell = xv * lr - __expf(lr) - lg;
  blk_reduce_add(ell, ell_acc);
}

// mean and unbiased variance over S
__global__ void k_mv(const float* __restrict__ zs, float* __restrict__ m, float* __restrict__ P){
  int i = blockIdx.x * 256 + threadIdx.x;   // (b,t,l) flat
  float x[S_];
  float s = 0.f;
  #pragma unroll
  for (int q = 0; q < S_; ++q){ x[q] = zs[q * (B_ * T_ * L_) + i]; s += x[q]; }
  float mu = s * (1.f / S_);
  float v = 0.f;
  #pragma unroll
  for (int q = 0; q < S_; ++q){ float dd = x[q] - mu; v = fmaf(dd, dd, v); }
  m[i] = mu;
  P[i] = v * (1.f / (S_ - 1));
}

__global__ void k_fin(const double* __restrict__ accs, float* __restrict__ out){
  double log_pxs = accs[0] / 4096.0;
  double logqp0 = accs[1] / 256.0;
  double logqp_path = 0.5 * 0.02 * accs[2] / 4096.0;
  out[0] = (float)(-log_pxs + logqp0 + logqp_path);
}

extern "C" void kernel_launch(void* const* d_in, const int* in_sizes, int n_in,
                              void* d_out, int out_size, void* d_ws, size_t ws_size,
                              hipStream_t stream) {
  const float* xs_pre = (const float*)d_in[0];
  const float* eps0   = (const float*)d_in[1];
  const float* dW     = (const float*)d_in[2];
  const float* Wih    = (const float*)d_in[3];
  const float* Whh    = (const float*)d_in[4];
  const float* bih    = (const float*)d_in[5];
  const float* bhh    = (const float*)d_in[6];
  const float* encW   = (const float*)d_in[7];
  const float* encb   = (const float*)d_in[8];
  const float* qW     = (const float*)d_in[9];
  const float* qb     = (const float*)d_in[10];
  const float* fW1    = (const float*)d_in[11];
  const float* fb1    = (const float*)d_in[12];
  const float* fW2    = (const float*)d_in[13];
  const float* fb2    = (const float*)d_in[14];
  const float* fW3    = (const float*)d_in[15];
  const float* fb3    = (const float*)d_in[16];
  const float* hW1    = (const float*)d_in[17];
  const float* hb1    = (const float*)d_in[18];
  const float* hW2    = (const float*)d_in[19];
  const float* hb2    = (const float*)d_in[20];
  const float* hW3    = (const float*)d_in[21];
  const float* hb3    = (const float*)d_in[22];
  const float* gW1    = (const float*)d_in[23];
  const float* gb1    = (const float*)d_in[24];
  const float* gW2    = (const float*)d_in[25];
  const float* gb2    = (const float*)d_in[26];
  const float* pm     = (const float*)d_in[27];
  const float* pls    = (const float*)d_in[28];
  const float* Cw     = (const float*)d_in[29];
  const float* db     = (const float*)d_in[30];

  float* out = (float*)d_out;
  float* zs  = out + 1;                      // (S,B,T,L)
  float* m   = out + 1 + 16777216;           // (B,T,L)
  float* P   = m + 1048576;

  // workspace layout
  double* accs = (double*)d_ws;              // [0]=ell, [1]=kl, [2]=u2
  float* wf = (float*)d_ws + 16;
  float* xT   = wf; wf += T_ * D_ * B_;      // 4,194,304
  float* hsT  = wf; wf += T_ * H_ * B_;      // 8,388,608
  float* ctxT = wf; wf += T_ * C_ * B_;      // 2,097,152
  float* zbuf = wf; wf += 2 * L_ * R_;       // 262,144
  float* ab1T = wf; wf += 2 * H_ * R_;       // 2,097,152
  float* ab2T = wf; wf += 2 * H_ * R_;       // 2,097,152
  float* fhT  = wf; wf += 2 * L_ * R_;       // 262,144
  float* qmT  = wf; wf += L_ * B_;
  float* qlsT = wf; wf += L_ * B_;
  float* gW1T = wf; wf += 8192;
  float* gb1T = wf; wf += 8192;
  float* gW2T = wf; wf += 8192;
  size_t need = (size_t)(wf - (float*)d_ws) * 4;
  if (ws_size < need) return;  // workspace too small: fail loudly

  k_init<<<1, 64, 0, stream>>>(accs);
  k_tx<<<16384, 256, 0, stream>>>(xs_pre, xT);
  k_tsmall<<<96, 256, 0, stream>>>(gW1, gb1, gW2, gW1T, gb1T, gW2T);

  for (int k = 0; k < T_; ++k)
    k_gru<<<256, 256, 0, stream>>>(xT, Wih, Whh, bih, bhh, hsT, k);

  k_ctx<<<8192, 256, 0, stream>>>(hsT, encW, encb, ctxT);
  k_qz0<<<32, 256, 0, stream>>>(ctxT, qW, qb, pm, pls, qmT, qlsT, accs + 1);
  k_z0<<<16, 256, 0, stream>>>(eps0, qmT, qlsT, zbuf, zs);

  for (int k = 0; k < NT_; ++k){
    float* zc = zbuf + (k & 1) * (L_ * R_);
    float* zn = zbuf + ((k + 1) & 1) * (L_ * R_);
    int tctx = (k + 1 < T_ - 1) ? (k + 1) : (T_ - 1);
    k_l1<<<512, 256, 0, stream>>>(zc, ctxT, fW1, fb1, hW1, hb1, ab1T, tctx);
    k_l2<<<512, 256, 0, stream>>>(ab1T, fW2, fb2, hW2, hb2, ab2T);
    k_l3<<<128, 256, 0, stream>>>(ab2T, fW3, fb3, hW3, hb3, fhT);
    k_gu<<<512, 256, 0, stream>>>(zc, fhT, gW1T, gb1T, gW2T, gb2, dW, zn, zs, accs + 2, k);
  }

  k_pois<<<262144, 256, 0, stream>>>(zs, Cw, db, xs_pre, accs + 0);
  k_mv<<<4096, 256, 0, stream>>>(zs, m, P);
  k_fin<<<1, 1, 0, stream>>>(accs, out);
}